// Round 1
// baseline (297.185 us; speedup 1.0000x reference)
//
#include <hip/hip_runtime.h>

#define N_ROWS 32768
#define DDIM 128
#define KCODES 1024
#define BM 32
#define BN 256
#define BKC 32
#define ESTRIDE 36   // 32 + 4 floats: 144B row stride -> bank-balanced b128 access

// ---------------- s2[k] = sum_d e[d][k]^2 ----------------
__global__ __launch_bounds__(256) void vq_s2(const float* __restrict__ e,
                                             float* __restrict__ s2) {
    int k = blockIdx.x * 256 + threadIdx.x;
    float s = 0.f;
    for (int d = 0; d < DDIM; d++) {
        float v = e[(size_t)d * KCODES + k];
        s = fmaf(v, v, s);
    }
    s2[k] = s;
}

// ---------------- main: distances, argmin, quantized write, loss partial ----------------
__global__ __launch_bounds__(256) void vq_main(const float* __restrict__ x,
                                               const float* __restrict__ e,
                                               const float* __restrict__ s2,
                                               float* __restrict__ out_q,
                                               float* __restrict__ loss_acc) {
    __shared__ float xs[BM][DDIM];        // 16 KB
    __shared__ float es[BN][ESTRIDE];     // 36 KB, transposed e chunk [code][d]
    __shared__ float s1[BM];
    __shared__ float redv[BM][32];
    __shared__ int   redi[BM][32];
    __shared__ int   kmin_sh[BM];
    __shared__ float wsum[4];

    const int tid = threadIdx.x;
    const int row0 = blockIdx.x * BM;

    // stage x tile: 32 rows x 128 floats = 1024 float4, 4 per thread (coalesced)
    for (int i = 0; i < 4; i++) {
        int idx = tid + i * 256;          // float4 index in tile
        int r = idx >> 5;                 // 32 float4 per row
        int c4 = idx & 31;
        float4 v = ((const float4*)(x + (size_t)(row0 + r) * DDIM))[c4];
        *(float4*)&xs[r][c4 * 4] = v;
    }
    __syncthreads();
    if (tid < BM) {   // s1[r] = sum_d x^2, ascending-d fp32 (matches ref op order closely)
        float s = 0.f;
        for (int d = 0; d < DDIM; d++) { float v = xs[tid][d]; s = fmaf(v, v, s); }
        s1[tid] = s;
    }

    const int lane_c = tid & 31;          // 32 code groups (codes interleaved by 32)
    const int lane_r = tid >> 5;          // 8 row groups x 4 rows

    float bestv[4];
    int   besti[4];
    for (int i = 0; i < 4; i++) { bestv[i] = 3.4e38f; besti[i] = 0x7fffffff; }

    for (int kt = 0; kt < KCODES / BN; kt++) {
        const int kbase = kt * BN;
        float acc[4][8];
        for (int i = 0; i < 4; i++)
            for (int j = 0; j < 8; j++) acc[i][j] = 0.f;

        for (int dc = 0; dc < DDIM / BKC; dc++) {
            const int d0 = dc * BKC;
            __syncthreads();   // protect es from previous iteration's readers
            // stage e chunk transposed: thread owns code c=tid, 8 float4 (32 d's)
            {
                const float* ecol = e + (size_t)d0 * KCODES + (kbase + tid);
                for (int q = 0; q < BKC / 4; q++) {
                    float a0 = ecol[(size_t)(q * 4 + 0) * KCODES];
                    float a1 = ecol[(size_t)(q * 4 + 1) * KCODES];
                    float a2 = ecol[(size_t)(q * 4 + 2) * KCODES];
                    float a3 = ecol[(size_t)(q * 4 + 3) * KCODES];
                    *(float4*)&es[tid][q * 4] = make_float4(a0, a1, a2, a3);
                }
            }
            __syncthreads();
            // accumulate sims: 4 rows x 8 codes per thread
            for (int q = 0; q < BKC / 4; q++) {
                float4 xa[4];
                for (int i = 0; i < 4; i++)
                    xa[i] = *(const float4*)&xs[lane_r * 4 + i][d0 + q * 4];
                for (int j = 0; j < 8; j++) {
                    float4 eb = *(const float4*)&es[lane_c + 32 * j][q * 4];
                    for (int i = 0; i < 4; i++) {
                        acc[i][j] = fmaf(xa[i].x, eb.x, acc[i][j]);
                        acc[i][j] = fmaf(xa[i].y, eb.y, acc[i][j]);
                        acc[i][j] = fmaf(xa[i].z, eb.z, acc[i][j]);
                        acc[i][j] = fmaf(xa[i].w, eb.w, acc[i][j]);
                    }
                }
            }
        }
        // distances + running argmin (first-min tie-break like jnp.argmin)
        for (int i = 0; i < 4; i++) {
            float s1v = s1[lane_r * 4 + i];
            for (int j = 0; j < 8; j++) {
                int c = kbase + lane_c + 32 * j;
                float dist = (s1v + s2[c]) - 2.0f * acc[i][j];
                if (dist < bestv[i] || (dist == bestv[i] && c < besti[i])) {
                    bestv[i] = dist; besti[i] = c;
                }
            }
        }
    }

    // cross-thread argmin merge per row
    for (int i = 0; i < 4; i++) {
        redv[lane_r * 4 + i][lane_c] = bestv[i];
        redi[lane_r * 4 + i][lane_c] = besti[i];
    }
    __syncthreads();
    if (tid < BM) {
        float bv = redv[tid][0]; int bi = redi[tid][0];
        for (int l = 1; l < 32; l++) {
            float v = redv[tid][l]; int ii = redi[tid][l];
            if (v < bv || (v == bv && ii < bi)) { bv = v; bi = ii; }
        }
        kmin_sh[tid] = bi;
    }
    __syncthreads();

    // epilogue: write quantized (== quantized_st forward value) + loss partial
    float lsum = 0.f;
    {
        int r = tid >> 3;                  // 8 threads per row
        int dbase = (tid & 7) * 16;        // 16 consecutive d's each
        int km = kmin_sh[r];
        size_t obase = (size_t)(row0 + r) * DDIM;
        for (int t4 = 0; t4 < 4; t4++) {
            int d = dbase + t4 * 4;
            float q0 = e[(size_t)(d + 0) * KCODES + km];
            float q1 = e[(size_t)(d + 1) * KCODES + km];
            float q2 = e[(size_t)(d + 2) * KCODES + km];
            float q3 = e[(size_t)(d + 3) * KCODES + km];
            *(float4*)&out_q[obase + d] = make_float4(q0, q1, q2, q3);
            float f0 = q0 - xs[r][d + 0];
            float f1 = q1 - xs[r][d + 1];
            float f2 = q2 - xs[r][d + 2];
            float f3 = q3 - xs[r][d + 3];
            lsum = fmaf(f0, f0, lsum);
            lsum = fmaf(f1, f1, lsum);
            lsum = fmaf(f2, f2, lsum);
            lsum = fmaf(f3, f3, lsum);
        }
    }
    // block reduction of loss partial
    for (int off = 32; off > 0; off >>= 1)
        lsum += __shfl_down(lsum, off, 64);
    if ((tid & 63) == 0) wsum[tid >> 6] = lsum;
    __syncthreads();
    if (tid == 0) {
        float t = wsum[0] + wsum[1] + wsum[2] + wsum[3];
        atomicAdd(loss_acc, t);
    }
}

// ---------------- code-to-code distances: second smallest + scales ----------------
__global__ __launch_bounds__(256) void vq_codedist(const float* __restrict__ e,
                                                   const float* __restrict__ s2,
                                                   float* __restrict__ out_scales) {
    __shared__ float ek[DDIM];
    __shared__ float m0s[256], m1s[256];
    __shared__ float second_sh;
    const int k = blockIdx.x;
    const int tid = threadIdx.x;
    if (tid < DDIM) ek[tid] = e[(size_t)tid * KCODES + k];
    __syncthreads();
    const float s2k = s2[k];
    float m0 = 3.4e38f, m1 = 3.4e38f;
    for (int j = tid; j < KCODES; j += 256) {
        float sim = 0.f;
        for (int d = 0; d < DDIM; d++)
            sim = fmaf(ek[d], e[(size_t)d * KCODES + j], sim);
        float dist = (s2k + s2[j]) - 2.0f * sim;
        if (dist < m0) { m1 = m0; m0 = dist; }
        else if (dist < m1) { m1 = dist; }
    }
    m0s[tid] = m0; m1s[tid] = m1;
    __syncthreads();
    if (tid == 0) {
        float a0 = 3.4e38f, a1 = 3.4e38f;
        for (int t = 0; t < 256; t++) {
            float v0 = m0s[t], v1 = m1s[t];
            if (v0 < a0) { a1 = fminf(a0, v1); a0 = v0; }
            else         { a1 = fminf(a1, v0); }
        }
        second_sh = a1;
    }
    __syncthreads();
    float scale = second_sh * (1.0f / 64.0f);   // / (D/2), exact pow2
    if (tid < DDIM)
        out_scales[(size_t)k * DDIM + tid] = scale;
}

// ---------------- loss finalize ----------------
__global__ void vq_finalize(const float* __restrict__ loss_acc,
                            float* __restrict__ out_loss) {
    float m = loss_acc[0] * (1.0f / 4194304.0f);  // mean over 64*512*128, exact pow2
    out_loss[0] = 0.25f * m + m;                  // commitment(BETA=0.25) + codebook
}

extern "C" void kernel_launch(void* const* d_in, const int* in_sizes, int n_in,
                              void* d_out, int out_size, void* d_ws, size_t ws_size,
                              hipStream_t stream) {
    const float* x = (const float*)d_in[0];
    const float* e = (const float*)d_in[1];
    float* out_q      = (float*)d_out;
    float* out_loss   = out_q + (size_t)N_ROWS * DDIM;
    float* out_scales = out_loss + 1;

    float* loss_acc = (float*)d_ws;
    float* s2       = (float*)((char*)d_ws + 16);

    hipMemsetAsync(d_ws, 0, 16, stream);
    vq_s2<<<KCODES / 256, 256, 0, stream>>>(e, s2);
    vq_main<<<N_ROWS / BM, 256, 0, stream>>>(x, e, s2, out_q, loss_acc);
    vq_codedist<<<KCODES, 256, 0, stream>>>(e, s2, out_scales);
    vq_finalize<<<1, 1, 0, stream>>>(loss_acc, out_loss);
}

// Round 2
// 254.458 us; speedup vs baseline: 1.1679x; 1.1679x over previous
//
#include <hip/hip_runtime.h>

typedef __attribute__((ext_vector_type(8))) short bf16x8;
typedef __attribute__((ext_vector_type(4))) float f32x4;

#define NROWS 32768
#define KC 1024
#define DD 128
#define BLKM 64
#define EPS_GAP 1e-3f

__device__ __forceinline__ unsigned short f2bf(float f) {
    unsigned u = __float_as_uint(f);
    unsigned r = u + 0x7FFFu + ((u >> 16) & 1u);
    return (unsigned short)(r >> 16);
}
__device__ __forceinline__ float bf2f(unsigned short h) {
    return __uint_as_float(((unsigned)h) << 16);
}

// ---------- prep: e -> bf16 hi/lo in B-fragment order; s2[k] ----------
// es_sw layout: [g (8)][code (1024)][quad (4)][j (8)] bf16 -> 64 B per (g, code).
// g 0..3 = e_hi for d-tiles 0..3; g 4..7 = e_lo for d-tiles 0..3.
__global__ __launch_bounds__(256) void k_prep(const float* __restrict__ e,
                                              unsigned short* __restrict__ es_sw,
                                              float* __restrict__ s2g) {
    int b = blockIdx.x, tid = threadIdx.x;
    if (b < 128) {
        int d = b;
        int g_hi = d >> 5, q = (d >> 3) & 3, j = d & 7;
        for (int it = 0; it < 4; it++) {
            int c = it * 256 + tid;
            float f = e[(size_t)d * KC + c];
            unsigned short hi = f2bf(f);
            unsigned short lo = f2bf(f - bf2f(hi));
            es_sw[((size_t)(g_hi * KC + c)) * 32 + q * 8 + j] = hi;
            es_sw[((size_t)((4 + g_hi) * KC + c)) * 32 + q * 8 + j] = lo;
        }
    } else {
        int k = (b - 128) * 256 + tid;
        float s = 0.f;
        for (int d = 0; d < DD; d++) { float v = e[(size_t)d * KC + k]; s = fmaf(v, v, s); }
        s2g[k] = s;
    }
}

// ---------- main: split-bf16 MFMA distances + top-2 argmin ----------
__global__ __launch_bounds__(256, 2) void k_main(const float* __restrict__ x,
                                                 const unsigned short* __restrict__ es_sw,
                                                 const float* __restrict__ s2g,
                                                 int* __restrict__ idxg,
                                                 int* __restrict__ flagg) {
    __shared__ short As[16384];            // 32 KB: 32 segs (a*4+mt) x 64 lanes x 8 bf16
    __shared__ float s2s[1024];            // 4 KB
    __shared__ float rv0[4][64];
    __shared__ float rv1[4][64];
    __shared__ int   ri0[4][64];

    const int tid  = threadIdx.x;
    const int w    = tid >> 6, lane = tid & 63;
    const int quad = lane >> 4, col = lane & 15;
    const int row0 = blockIdx.x * BLKM;

    // ---- stage A: convert x rows to bf16 hi/lo directly in fragment order ----
    // hi chunk ch (0..1023): seg = ch>>6 = akt*4+mt, quad=(ch>>4)&3, m=ch&15
    // lo goes to chunk ch+1024 (segs 16..31), same (row, d) source.
    #pragma unroll
    for (int it = 0; it < 4; it++) {
        int ch = it * 256 + tid;
        int seg = ch >> 6;
        int akt = seg >> 2, mt = seg & 3;
        int q = (ch >> 4) & 3, m = ch & 15;
        const float* xp = x + (size_t)(row0 + mt * 16 + m) * DD + akt * 32 + q * 8;
        float4 xa = *(const float4*)xp;
        float4 xb = *(const float4*)(xp + 4);
        float xv[8] = {xa.x, xa.y, xa.z, xa.w, xb.x, xb.y, xb.z, xb.w};
        bf16x8 h, l;
        #pragma unroll
        for (int j = 0; j < 8; j++) {
            unsigned short hv = f2bf(xv[j]);
            h[j] = (short)hv;
            l[j] = (short)f2bf(xv[j] - bf2f(hv));
        }
        *(bf16x8*)&As[ch * 8] = h;
        *(bf16x8*)&As[(ch + 1024) * 8] = l;
    }
    ((float4*)s2s)[tid] = ((const float4*)s2g)[tid];
    __syncthreads();

    float bv0[16], bv1[16]; int bi0[16];
    #pragma unroll
    for (int s = 0; s < 16; s++) { bv0[s] = 3.4e38f; bv1[s] = 3.4e38f; bi0[s] = 0x7fffffff; }

    const char* esb = (const char*)es_sw;
    const size_t lane_off = (size_t)(col * 64 + quad * 16);

    bf16x8 bc[4], bn[4];
    {   // preload step 0: ct=0, kt=0 -> g=0, cb=w*64
        const char* p0 = esb + (size_t)(w * 64) * 64 + lane_off;
        #pragma unroll
        for (int nt = 0; nt < 4; nt++)
            bc[nt] = *(const bf16x8*)(p0 + nt * 1024);
    }

    #pragma unroll 1
    for (int ct = 0; ct < 4; ct++) {
        f32x4 acc[4][4];
        #pragma unroll
        for (int mt = 0; mt < 4; mt++)
            #pragma unroll
            for (int nt = 0; nt < 4; nt++)
                acc[mt][nt] = (f32x4){0.f, 0.f, 0.f, 0.f};

        #pragma unroll
        for (int kt = 0; kt < 12; kt++) {
            // prefetch next step's B frags (register double-buffer)
            int kn = kt + 1, cn = ct;
            if (kn == 12) { kn = 0; cn++; }
            if (cn < 4) {
                int g = kn < 8 ? kn : kn - 8;
                const char* p = esb + (size_t)(g * KC + cn * 256 + w * 64) * 64 + lane_off;
                #pragma unroll
                for (int nt = 0; nt < 4; nt++)
                    bn[nt] = *(const bf16x8*)(p + nt * 1024);
            }
            int a = kt < 4 ? kt : kt - 4;     // kt 0-7: hi segs 0-3; kt 8-11: lo segs 4-7
            bf16x8 af[4];
            #pragma unroll
            for (int mt = 0; mt < 4; mt++)
                af[mt] = *(const bf16x8*)&As[((a * 4 + mt) * 64 + lane) * 8];
            #pragma unroll
            for (int mt = 0; mt < 4; mt++)
                #pragma unroll
                for (int nt = 0; nt < 4; nt++)
                    acc[mt][nt] = __builtin_amdgcn_mfma_f32_16x16x32_bf16(af[mt], bc[nt], acc[mt][nt], 0, 0, 0);
            #pragma unroll
            for (int nt = 0; nt < 4; nt++) bc[nt] = bn[nt];
        }

        // fold distances into per-lane top-2 (codes ascend: ct, then nt)
        int cb = ct * 256 + w * 64;
        #pragma unroll
        for (int nt = 0; nt < 4; nt++) {
            int c = cb + nt * 16 + col;
            float s2c = s2s[c];
            #pragma unroll
            for (int mt = 0; mt < 4; mt++)
                #pragma unroll
                for (int r = 0; r < 4; r++) {
                    float d = fmaf(-2.f, acc[mt][nt][r], s2c);
                    int slot = mt * 4 + r;
                    if (d < bv0[slot]) { bv1[slot] = bv0[slot]; bv0[slot] = d; bi0[slot] = c; }
                    else if (d < bv1[slot]) bv1[slot] = d;
                }
        }
    }

    // butterfly top-2 merge across the 16 col-lanes (same quad group)
    #pragma unroll
    for (int msk = 1; msk < 16; msk <<= 1) {
        #pragma unroll
        for (int s = 0; s < 16; s++) {
            float u0 = __shfl_xor(bv0[s], msk, 64);
            float u1 = __shfl_xor(bv1[s], msk, 64);
            int   j0 = __shfl_xor(bi0[s], msk, 64);
            if (u0 < bv0[s] || (u0 == bv0[s] && j0 < bi0[s])) {
                bv1[s] = fminf(bv0[s], u1); bv0[s] = u0; bi0[s] = j0;
            } else {
                bv1[s] = fminf(bv1[s], u0);
            }
        }
    }
    if (col == 0) {
        #pragma unroll
        for (int s = 0; s < 16; s++) {
            int mt = s >> 2, r = s & 3;
            int row = mt * 16 + quad * 4 + r;
            rv0[w][row] = bv0[s]; rv1[w][row] = bv1[s]; ri0[w][row] = bi0[s];
        }
    }
    __syncthreads();
    if (tid < 64) {
        float v0 = rv0[0][tid], v1 = rv1[0][tid]; int i0 = ri0[0][tid];
        for (int ww = 1; ww < 4; ww++) {
            float u0 = rv0[ww][tid], u1 = rv1[ww][tid]; int j0 = ri0[ww][tid];
            if (u0 < v0 || (u0 == v0 && j0 < i0)) { v1 = fminf(v0, u1); v0 = u0; i0 = j0; }
            else v1 = fminf(v1, u0);
        }
        idxg[row0 + tid] = i0;
        flagg[row0 + tid] = (v1 - v0 < EPS_GAP) ? 1 : 0;
    }
}

// ---------- out: exact fallback for near-ties, gather quantized, loss ----------
__global__ __launch_bounds__(256) void k_out(const float* __restrict__ x,
                                             const float* __restrict__ e,
                                             const float* __restrict__ s2g,
                                             const int* __restrict__ idxg,
                                             const int* __restrict__ flagg,
                                             float* __restrict__ out_q,
                                             float* __restrict__ loss_acc) {
    __shared__ int   kml[64];
    __shared__ int   flv[64];
    __shared__ float xrow[128];
    __shared__ float rv[256];
    __shared__ int   ri[256];
    __shared__ float wsum[4];
    const int tid = threadIdx.x;
    const int row0 = blockIdx.x * 64;

    if (tid < 64) { kml[tid] = idxg[row0 + tid]; flv[tid] = flagg[row0 + tid]; }
    __syncthreads();

    for (int r = 0; r < 64; r++) {
        if (flv[r]) {   // uniform branch: exact fp32 re-argmin for this row
            if (tid < 32) ((float4*)xrow)[tid] = ((const float4*)(x + (size_t)(row0 + r) * DD))[tid];
            __syncthreads();
            int c0 = tid * 4;
            float s0 = 0.f, s1 = 0.f, s2 = 0.f, s3 = 0.f;
            for (int d = 0; d < DD; d++) {
                float xv = xrow[d];
                float4 ev = *(const float4*)(e + (size_t)d * KC + c0);
                s0 = fmaf(xv, ev.x, s0); s1 = fmaf(xv, ev.y, s1);
                s2 = fmaf(xv, ev.z, s2); s3 = fmaf(xv, ev.w, s3);
            }
            float dv0 = s2g[c0 + 0] - 2.f * s0;
            float dv1 = s2g[c0 + 1] - 2.f * s1;
            float dv2 = s2g[c0 + 2] - 2.f * s2;
            float dv3 = s2g[c0 + 3] - 2.f * s3;
            float bv = dv0; int bi = c0;
            if (dv1 < bv) { bv = dv1; bi = c0 + 1; }
            if (dv2 < bv) { bv = dv2; bi = c0 + 2; }
            if (dv3 < bv) { bv = dv3; bi = c0 + 3; }
            rv[tid] = bv; ri[tid] = bi;
            __syncthreads();
            if (tid == 0) {
                float b = rv[0]; int bidx = ri[0];
                for (int t = 1; t < 256; t++)
                    if (rv[t] < b) { b = rv[t]; bidx = ri[t]; }
                kml[r] = bidx;
            }
            __syncthreads();
        }
    }
    __syncthreads();

    // gather quantized + loss partial (4 threads per row, 32 d each)
    float lsum = 0.f;
    {
        int r = tid >> 2, t4 = tid & 3;
        int km = kml[r];
        size_t rowg = (size_t)row0 + r;
        int d0 = t4 * 32;
        const float* xr = x + rowg * DD;
        float* oq = out_q + rowg * DD;
        #pragma unroll
        for (int i = 0; i < 8; i++) {
            int d = d0 + i * 4;
            float q0 = e[(size_t)(d + 0) * KC + km];
            float q1 = e[(size_t)(d + 1) * KC + km];
            float q2 = e[(size_t)(d + 2) * KC + km];
            float q3 = e[(size_t)(d + 3) * KC + km];
            *(float4*)(oq + d) = make_float4(q0, q1, q2, q3);
            float4 xv = *(const float4*)(xr + d);
            float f0 = q0 - xv.x, f1 = q1 - xv.y, f2 = q2 - xv.z, f3 = q3 - xv.w;
            lsum = fmaf(f0, f0, lsum); lsum = fmaf(f1, f1, lsum);
            lsum = fmaf(f2, f2, lsum); lsum = fmaf(f3, f3, lsum);
        }
    }
    for (int off = 32; off > 0; off >>= 1) lsum += __shfl_down(lsum, off, 64);
    if ((tid & 63) == 0) wsum[tid >> 6] = lsum;
    __syncthreads();
    if (tid == 0) atomicAdd(loss_acc, wsum[0] + wsum[1] + wsum[2] + wsum[3]);
}

// ---------- codedist: second-smallest code-to-code distance -> scales ----------
__global__ __launch_bounds__(256) void k_codedist(const float* __restrict__ e,
                                                  const float* __restrict__ s2g,
                                                  float* __restrict__ out_scales) {
    __shared__ float ek[4][128];     // 4 codes' vectors
    __shared__ float red0[4][256];
    __shared__ float red1[4][256];
    __shared__ float sc[4];
    const int tid = threadIdx.x;
    const int kb = blockIdx.x * 4;

    if (tid < 128) {
        float4 v = *(const float4*)(e + (size_t)tid * KC + kb);
        ek[0][tid] = v.x; ek[1][tid] = v.y; ek[2][tid] = v.z; ek[3][tid] = v.w;
    }
    __syncthreads();

    float s2k0 = s2g[kb + 0], s2k1 = s2g[kb + 1], s2k2 = s2g[kb + 2], s2k3 = s2g[kb + 3];
    float m0[4] = {3.4e38f, 3.4e38f, 3.4e38f, 3.4e38f};
    float m1[4] = {3.4e38f, 3.4e38f, 3.4e38f, 3.4e38f};
    for (int jj = 0; jj < 4; jj++) {
        int j = jj * 256 + tid;
        float s0 = 0.f, s1 = 0.f, s2 = 0.f, s3 = 0.f;
        for (int d = 0; d < DD; d++) {
            float ev = e[(size_t)d * KC + j];
            s0 = fmaf(ek[0][d], ev, s0); s1 = fmaf(ek[1][d], ev, s1);
            s2 = fmaf(ek[2][d], ev, s2); s3 = fmaf(ek[3][d], ev, s3);
        }
        float s2j = s2g[j];
        float dd0 = (s2k0 + s2j) - 2.f * s0;
        float dd1 = (s2k1 + s2j) - 2.f * s1;
        float dd2 = (s2k2 + s2j) - 2.f * s2;
        float dd3 = (s2k3 + s2j) - 2.f * s3;
        if (dd0 < m0[0]) { m1[0] = m0[0]; m0[0] = dd0; } else if (dd0 < m1[0]) m1[0] = dd0;
        if (dd1 < m0[1]) { m1[1] = m0[1]; m0[1] = dd1; } else if (dd1 < m1[1]) m1[1] = dd1;
        if (dd2 < m0[2]) { m1[2] = m0[2]; m0[2] = dd2; } else if (dd2 < m1[2]) m1[2] = dd2;
        if (dd3 < m0[3]) { m1[3] = m0[3]; m0[3] = dd3; } else if (dd3 < m1[3]) m1[3] = dd3;
    }
    #pragma unroll
    for (int i = 0; i < 4; i++) { red0[i][tid] = m0[i]; red1[i][tid] = m1[i]; }
    __syncthreads();
    if (tid < 4) {
        float a0 = 3.4e38f, a1 = 3.4e38f;
        for (int t = 0; t < 256; t++) {
            float v0 = red0[tid][t], v1 = red1[tid][t];
            if (v0 < a0) { a1 = fminf(a0, v1); a0 = v0; }
            else a1 = fminf(a1, v0);
        }
        sc[tid] = a1 * (1.0f / 64.0f);   // second_smallest / (D/2)
    }
    __syncthreads();
    if (tid < 128) {
        #pragma unroll
        for (int i = 0; i < 4; i++)
            out_scales[(size_t)(kb + i) * DD + tid] = sc[i];
    }
}

// ---------- finalize loss ----------
__global__ void k_finalize(const float* __restrict__ loss_acc,
                           float* __restrict__ out_loss) {
    float m = loss_acc[0] * (1.0f / 4194304.0f);
    out_loss[0] = 0.25f * m + m;
}

extern "C" void kernel_launch(void* const* d_in, const int* in_sizes, int n_in,
                              void* d_out, int out_size, void* d_ws, size_t ws_size,
                              hipStream_t stream) {
    const float* x = (const float*)d_in[0];
    const float* e = (const float*)d_in[1];
    float* out_q      = (float*)d_out;
    float* out_loss   = out_q + (size_t)NROWS * DD;
    float* out_scales = out_loss + 1;

    char* ws = (char*)d_ws;
    float* loss_acc          = (float*)(ws + 0);
    float* s2g               = (float*)(ws + 1024);
    int*   idxg              = (int*)(ws + 8192);
    int*   flagg             = (int*)(ws + 139264);
    unsigned short* es_sw    = (unsigned short*)(ws + 270336);

    hipMemsetAsync(loss_acc, 0, 16, stream);
    k_prep<<<132, 256, 0, stream>>>(e, es_sw, s2g);
    k_main<<<NROWS / BLKM, 256, 0, stream>>>(x, es_sw, s2g, idxg, flagg);
    k_codedist<<<KC / 4, 256, 0, stream>>>(e, s2g, out_scales);
    k_out<<<NROWS / 64, 256, 0, stream>>>(x, e, s2g, idxg, flagg, out_q, loss_acc);
    k_finalize<<<1, 1, 0, stream>>>(loss_acc, out_loss);
}

// Round 3
// 225.442 us; speedup vs baseline: 1.3182x; 1.1287x over previous
//
#include <hip/hip_runtime.h>

typedef __attribute__((ext_vector_type(8))) short bf16x8;
typedef __attribute__((ext_vector_type(16))) float f32x16;

#define NROWS 32768
#define KC 1024
#define DD 128
#define EPS_GAP 1e-3f

typedef const unsigned int __attribute__((address_space(1)))* gp1_t;
typedef unsigned int __attribute__((address_space(3)))* lp3_t;

__device__ __forceinline__ unsigned short f2bf(float f) {
    unsigned u = __float_as_uint(f);
    unsigned r = u + 0x7FFFu + ((u >> 16) & 1u);
    return (unsigned short)(r >> 16);
}
__device__ __forceinline__ float bf2f(unsigned short h) {
    return __uint_as_float(((unsigned)h) << 16);
}

// ---------- prep: e -> bf16 hi/lo A-fragment order (32x32x16), eT, s2 ----------
// a_sw frag (ct 0..15, slot 0..15, mt 0..1): 1024 B each; slot 0-7 = e_hi(kd), 8-15 = e_lo(kd).
// lane l of frag holds A[m = l&31][k = (l>>5)*8 + j]: code = ct*64+mt*32+m, d = kd*16+(l>>5)*8+j.
__global__ __launch_bounds__(256) void k_prep(const float* __restrict__ e,
                                              unsigned short* __restrict__ a_sw,
                                              float* __restrict__ eT,
                                              float* __restrict__ s2g) {
    int c = blockIdx.x * 256 + threadIdx.x;
    int ct = c >> 6, mt = (c >> 5) & 1, m = c & 31;
    float s = 0.f;
    for (int kd = 0; kd < 8; kd++) {
        #pragma unroll
        for (int h = 0; h < 2; h++) {
            int d0 = kd * 16 + h * 8;
            float v[8]; bf16x8 hi8, lo8;
            #pragma unroll
            for (int j = 0; j < 8; j++) {
                float f = e[(size_t)(d0 + j) * KC + c];
                v[j] = f;
                unsigned short hh = f2bf(f);
                hi8[j] = (short)hh;
                lo8[j] = (short)f2bf(f - bf2f(hh));
                s = fmaf(f, f, s);
            }
            *(float4*)&eT[(size_t)c * DD + d0]     = make_float4(v[0], v[1], v[2], v[3]);
            *(float4*)&eT[(size_t)c * DD + d0 + 4] = make_float4(v[4], v[5], v[6], v[7]);
            size_t fb_hi = ((size_t)((ct * 16 + kd)     * 2 + mt)) * 512 + (h * 32 + m) * 8;
            size_t fb_lo = ((size_t)((ct * 16 + 8 + kd) * 2 + mt)) * 512 + (h * 32 + m) * 8;
            *(bf16x8*)&a_sw[fb_hi] = hi8;
            *(bf16x8*)&a_sw[fb_lo] = lo8;
        }
    }
    s2g[c] = s;
}

// ---------- main: transposed split-bf16 MFMA + top-2 argmin + fused epilogue ----------
__global__ __launch_bounds__(256, 1) void k_main(const float* __restrict__ x,
                                                 const unsigned short* __restrict__ a_sw,
                                                 const float* __restrict__ eT,
                                                 const float* __restrict__ s2g,
                                                 int* __restrict__ idxg,
                                                 float* __restrict__ out_q,
                                                 double* __restrict__ loss_acc) {
    __shared__ short es[2][16384];   // 2 x 32 KB A-tile double buffer
    __shared__ float s2s[1024];      // 4 KB

    const int tid = threadIdx.x;
    const int w = tid >> 6, lane = tid & 63;
    const int halfk = lane >> 5, col = lane & 31;
    const int row0 = blockIdx.x * 128;
    const int myrow = row0 + w * 32 + col;

    // ---- x fragments (persistent in registers): hi + lo, B-operand layout ----
    const float* xr = x + (size_t)myrow * DD;
    bf16x8 xh[8], xl[8];
    #pragma unroll
    for (int kd = 0; kd < 8; kd++) {
        const float* p = xr + kd * 16 + halfk * 8;
        float4 a = *(const float4*)p;
        float4 b = *(const float4*)(p + 4);
        float v[8] = {a.x, a.y, a.z, a.w, b.x, b.y, b.z, b.w};
        #pragma unroll
        for (int j = 0; j < 8; j++) {
            unsigned short h = f2bf(v[j]);
            xh[kd][j] = (short)h;
            xl[kd][j] = (short)f2bf(v[j] - bf2f(h));
        }
    }
    ((float4*)s2s)[tid] = ((const float4*)s2g)[tid];

    // ---- stage helper: 32 KB A-tile for code-tile ct via global_load_lds ----
    const char* a_base = (const char*)a_sw;
    #define STAGE(ct_, buf_) {                                            \
        const char* src_ = a_base + (size_t)(ct_) * 32768;                \
        char* dst_ = (char*)&es[(buf_)][0];                               \
        _Pragma("unroll")                                                 \
        for (int i_ = 0; i_ < 8; i_++) {                                  \
            int off_ = (i_ * 4 + w) * 1024;                               \
            __builtin_amdgcn_global_load_lds((gp1_t)(const void*)(src_ + off_ + lane * 16), \
                                             (lp3_t)(void*)(dst_ + off_), 16, 0, 0); \
        }                                                                 \
    }

    STAGE(0, 0);
    __syncthreads();

    float bv0 = 3.4e38f, bv1 = 3.4e38f;
    int bi0 = 0x7fffffff;

    #pragma unroll 1
    for (int ct = 0; ct < 16; ct++) {
        int buf = ct & 1;
        if (ct + 1 < 16) STAGE(ct + 1, buf ^ 1);

        f32x16 acc0, acc1;
        #pragma unroll
        for (int r = 0; r < 16; r++) { acc0[r] = 0.f; acc1[r] = 0.f; }

        const short* eb = &es[buf][0];
        // 24 K-steps: s 0-7: e_hi x x_hi; 8-15: e_lo x x_hi; 16-23: e_hi x x_lo
        #pragma unroll
        for (int s = 0; s < 24; s++) {
            int slot = (s < 16) ? s : (s - 16);
            bf16x8 b = (s < 8) ? xh[s] : (s < 16 ? xh[s - 8] : xl[s - 16]);
            const short* f0 = &eb[(slot * 2 + 0) * 512 + lane * 8];
            bf16x8 a0 = *(const bf16x8*)f0;
            bf16x8 a1 = *(const bf16x8*)(f0 + 512);
            acc0 = __builtin_amdgcn_mfma_f32_32x32x16_bf16(a0, b, acc0, 0, 0, 0);
            acc1 = __builtin_amdgcn_mfma_f32_32x32x16_bf16(a1, b, acc1, 0, 0, 0);
        }

        // fold distances: code = ct*64 + mt*32 + 4*halfk + g*8 + q  (reg r=g*4+q)
        int cb = ct * 64 + 4 * halfk;
        #pragma unroll
        for (int mt = 0; mt < 2; mt++) {
            #pragma unroll
            for (int g = 0; g < 4; g++) {
                float4 s2v = *(const float4*)&s2s[cb + mt * 32 + g * 8];
                const float* s2p = (const float*)&s2v;
                #pragma unroll
                for (int q = 0; q < 4; q++) {
                    int r = g * 4 + q;
                    float av = mt ? acc1[r] : acc0[r];
                    float dv = fmaf(-2.f, av, s2p[q]);
                    int c = cb + mt * 32 + g * 8 + q;
                    bool lt = dv < bv0;
                    bv1 = fminf(bv1, fmaxf(bv0, dv));
                    bv0 = fminf(bv0, dv);
                    bi0 = lt ? c : bi0;
                }
            }
        }
        __syncthreads();
    }

    // ---- merge the two k-halves (lanes l and l^32 share the same x-row) ----
    float u0 = __shfl_xor(bv0, 32, 64);
    float u1 = __shfl_xor(bv1, 32, 64);
    int   j0 = __shfl_xor(bi0, 32, 64);
    float v0, v1; int i0;
    if (u0 < bv0 || (u0 == bv0 && j0 < bi0)) { v0 = u0; i0 = j0; v1 = fminf(u1, bv0); }
    else                                     { v0 = bv0; i0 = bi0; v1 = fminf(bv1, u0); }

    int flag = (v1 - v0 < EPS_GAP) ? 1 : 0;
    int packed = i0 | (flag << 31);
    if (lane < 32) idxg[myrow] = packed;

    // ---- fused epilogue: gather quantized + loss for non-flagged rows ----
    float lsum = 0.f;
    #pragma unroll 8
    for (int r = 0; r < 32; r++) {
        int pk = __shfl(packed, r, 64);
        if (pk >= 0) {
            size_t grow = (size_t)row0 + w * 32 + r;
            float2 q  = *(const float2*)&eT[(size_t)pk * DD + lane * 2];
            float2 xv = *(const float2*)&x[grow * DD + lane * 2];
            *(float2*)&out_q[grow * DD + lane * 2] = q;
            float f0 = q.x - xv.x, f1 = q.y - xv.y;
            lsum = fmaf(f0, f0, fmaf(f1, f1, lsum));
        }
    }
    #pragma unroll
    for (int off = 32; off > 0; off >>= 1) lsum += __shfl_down(lsum, off, 64);
    if (lane == 0) atomicAdd(loss_acc, (double)lsum);
}

// ---------- fix: exact fp32 re-argmin + output for flagged (near-tie) rows ----------
__global__ __launch_bounds__(256) void k_fix(const float* __restrict__ x,
                                             const float* __restrict__ e,
                                             const float* __restrict__ eT,
                                             const float* __restrict__ s2g,
                                             const int* __restrict__ idxg,
                                             float* __restrict__ out_q,
                                             double* __restrict__ loss_acc) {
    __shared__ int anyf;
    __shared__ float xrow[DD];
    __shared__ float rv[256];
    __shared__ int   ri[256];
    __shared__ int   kml;
    __shared__ float wred[2];
    const int tid = threadIdx.x;
    const int row0 = blockIdx.x * 64;

    if (tid == 0) anyf = 0;
    __syncthreads();
    if (tid < 64) { if (idxg[row0 + tid] < 0) anyf = 1; }
    __syncthreads();
    if (!anyf) return;

    for (int r = 0; r < 64; r++) {
        int pkr = idxg[row0 + r];
        if (pkr >= 0) continue;   // uniform per block
        if (tid < 32) ((float4*)xrow)[tid] = ((const float4*)(x + (size_t)(row0 + r) * DD))[tid];
        __syncthreads();
        int c0 = tid * 4;
        float s0 = 0.f, s1 = 0.f, s2 = 0.f, s3 = 0.f;
        for (int d = 0; d < DD; d++) {
            float xv = xrow[d];
            float4 ev = *(const float4*)(e + (size_t)d * KC + c0);
            s0 = fmaf(xv, ev.x, s0); s1 = fmaf(xv, ev.y, s1);
            s2 = fmaf(xv, ev.z, s2); s3 = fmaf(xv, ev.w, s3);
        }
        float dv0 = s2g[c0 + 0] - 2.f * s0;
        float dv1 = s2g[c0 + 1] - 2.f * s1;
        float dv2 = s2g[c0 + 2] - 2.f * s2;
        float dv3 = s2g[c0 + 3] - 2.f * s3;
        float bv = dv0; int bi = c0;
        if (dv1 < bv) { bv = dv1; bi = c0 + 1; }
        if (dv2 < bv) { bv = dv2; bi = c0 + 2; }
        if (dv3 < bv) { bv = dv3; bi = c0 + 3; }
        rv[tid] = bv; ri[tid] = bi;
        __syncthreads();
        if (tid == 0) {
            float b = rv[0]; int bidx = ri[0];
            for (int t = 1; t < 256; t++)
                if (rv[t] < b) { b = rv[t]; bidx = ri[t]; }
            kml = bidx;
        }
        __syncthreads();
        // write row + loss
        float ls = 0.f;
        if (tid < 128) {
            int km = kml;
            float q = eT[(size_t)km * DD + tid];
            float xv = xrow[tid];
            out_q[(size_t)(row0 + r) * DD + tid] = q;
            float f = q - xv;
            ls = f * f;
        }
        #pragma unroll
        for (int off = 32; off > 0; off >>= 1) ls += __shfl_down(ls, off, 64);
        if ((tid & 63) == 0 && tid < 128) wred[tid >> 6] = ls;
        __syncthreads();
        if (tid == 0) atomicAdd(loss_acc, (double)(wred[0] + wred[1]));
        __syncthreads();
    }
}

// ---------- codedist: second-smallest code-to-code distance -> scales ----------
__global__ __launch_bounds__(256) void k_codedist(const float* __restrict__ e,
                                                  const float* __restrict__ s2g,
                                                  float* __restrict__ out_scales) {
    __shared__ float ek[4][128];
    __shared__ float red0[4][256];
    __shared__ float red1[4][256];
    __shared__ float sc[4];
    const int tid = threadIdx.x;
    const int kb = blockIdx.x * 4;

    if (tid < 128) {
        float4 v = *(const float4*)(e + (size_t)tid * KC + kb);
        ek[0][tid] = v.x; ek[1][tid] = v.y; ek[2][tid] = v.z; ek[3][tid] = v.w;
    }
    __syncthreads();

    float s2k0 = s2g[kb + 0], s2k1 = s2g[kb + 1], s2k2 = s2g[kb + 2], s2k3 = s2g[kb + 3];
    float m0[4] = {3.4e38f, 3.4e38f, 3.4e38f, 3.4e38f};
    float m1[4] = {3.4e38f, 3.4e38f, 3.4e38f, 3.4e38f};
    for (int jj = 0; jj < 4; jj++) {
        int j = jj * 256 + tid;
        float s0 = 0.f, s1 = 0.f, s2 = 0.f, s3 = 0.f;
        for (int d = 0; d < DD; d++) {
            float ev = e[(size_t)d * KC + j];
            s0 = fmaf(ek[0][d], ev, s0); s1 = fmaf(ek[1][d], ev, s1);
            s2 = fmaf(ek[2][d], ev, s2); s3 = fmaf(ek[3][d], ev, s3);
        }
        float s2j = s2g[j];
        float dd0 = (s2k0 + s2j) - 2.f * s0;
        float dd1 = (s2k1 + s2j) - 2.f * s1;
        float dd2 = (s2k2 + s2j) - 2.f * s2;
        float dd3 = (s2k3 + s2j) - 2.f * s3;
        if (dd0 < m0[0]) { m1[0] = m0[0]; m0[0] = dd0; } else if (dd0 < m1[0]) m1[0] = dd0;
        if (dd1 < m0[1]) { m1[1] = m0[1]; m0[1] = dd1; } else if (dd1 < m1[1]) m1[1] = dd1;
        if (dd2 < m0[2]) { m1[2] = m0[2]; m0[2] = dd2; } else if (dd2 < m1[2]) m1[2] = dd2;
        if (dd3 < m0[3]) { m1[3] = m0[3]; m0[3] = dd3; } else if (dd3 < m1[3]) m1[3] = dd3;
    }
    #pragma unroll
    for (int i = 0; i < 4; i++) { red0[i][tid] = m0[i]; red1[i][tid] = m1[i]; }
    __syncthreads();
    if (tid < 4) {
        float a0 = 3.4e38f, a1 = 3.4e38f;
        for (int t = 0; t < 256; t++) {
            float v0 = red0[tid][t], v1 = red1[tid][t];
            if (v0 < a0) { a1 = fminf(a0, v1); a0 = v0; }
            else a1 = fminf(a1, v0);
        }
        sc[tid] = a1 * (1.0f / 64.0f);
    }
    __syncthreads();
    if (tid < 128) {
        #pragma unroll
        for (int i = 0; i < 4; i++)
            out_scales[(size_t)(kb + i) * DD + tid] = sc[i];
    }
}

// ---------- finalize ----------
__global__ void k_finalize(const double* __restrict__ loss_acc,
                           float* __restrict__ out_loss) {
    double m = loss_acc[0] / 4194304.0;
    out_loss[0] = (float)(0.25 * m + m);
}

extern "C" void kernel_launch(void* const* d_in, const int* in_sizes, int n_in,
                              void* d_out, int out_size, void* d_ws, size_t ws_size,
                              hipStream_t stream) {
    const float* x = (const float*)d_in[0];
    const float* e = (const float*)d_in[1];
    float* out_q      = (float*)d_out;
    float* out_loss   = out_q + (size_t)NROWS * DD;
    float* out_scales = out_loss + 1;

    char* ws = (char*)d_ws;
    double* loss_acc       = (double*)(ws + 0);
    float*  s2g            = (float*)(ws + 1024);
    int*    idxg           = (int*)(ws + 8192);
    float*  eT             = (float*)(ws + 139264);
    unsigned short* a_sw   = (unsigned short*)(ws + 663552);

    hipMemsetAsync(ws, 0, 16, stream);
    k_prep<<<4, 256, 0, stream>>>(e, a_sw, eT, s2g);
    k_main<<<NROWS / 128, 256, 0, stream>>>(x, a_sw, eT, s2g, idxg, out_q, loss_acc);
    k_fix<<<NROWS / 64, 256, 0, stream>>>(x, e, eT, s2g, idxg, out_q, loss_acc);
    k_codedist<<<KC / 4, 256, 0, stream>>>(e, s2g, out_scales);
    k_finalize<<<1, 1, 0, stream>>>(loss_acc, out_loss);
}

// Round 4
// 221.187 us; speedup vs baseline: 1.3436x; 1.0192x over previous
//
#include <hip/hip_runtime.h>

typedef __attribute__((ext_vector_type(8))) short bf16x8;
typedef __attribute__((ext_vector_type(16))) float f32x16;

#define NROWS 32768
#define KC 1024
#define DD 128
#define EPS_GAP 1e-3f

__device__ __forceinline__ unsigned short f2bf(float f) {
    unsigned u = __float_as_uint(f);
    unsigned r = u + 0x7FFFu + ((u >> 16) & 1u);
    return (unsigned short)(r >> 16);
}
__device__ __forceinline__ float bf2f(unsigned short h) {
    return __uint_as_float(((unsigned)h) << 16);
}

// ---------- prep: e -> bf16 hi/lo A-fragment order (32x32x16), eT, s2 ----------
// a_sw frag (ct 0..15, slot 0..15, mt 0..1): 1024 B each; slot 0-7 = e_hi(kd), 8-15 = e_lo(kd).
// lane l of frag holds A[m=l&31][k=(l>>5)*8+j]: code = ct*64+mt*32+m, d = kd*16+(l>>5)*8+j.
// Parallelized: blocks 0..127 = (ct,kd) tiles; blocks 128..131 = s2.
__global__ __launch_bounds__(256) void k_prep(const float* __restrict__ e,
                                              unsigned short* __restrict__ a_sw,
                                              float* __restrict__ eT,
                                              float* __restrict__ s2g) {
    const int b = blockIdx.x, tid = threadIdx.x;
    if (b < 128) {
        const int ct = b >> 3, kd = b & 7;
        const int mt = tid >> 7;           // 0..1
        const int l  = (tid >> 1) & 63;    // frag lane
        const int hj = (tid & 1) * 4;      // j half
        const int h = l >> 5, m = l & 31;
        const int c = ct * 64 + mt * 32 + m;
        const int d0 = kd * 16 + h * 8 + hj;
        float v[4];
        short hi[4], lo[4];
        #pragma unroll
        for (int jj = 0; jj < 4; jj++) {
            float f = e[(size_t)(d0 + jj) * KC + c];
            v[jj] = f;
            unsigned short hh = f2bf(f);
            hi[jj] = (short)hh;
            lo[jj] = (short)f2bf(f - bf2f(hh));
        }
        size_t frag_hi = ((size_t)((ct * 16 + kd) * 2 + mt)) * 512 + (h * 32 + m) * 8 + hj;
        char* ab = (char*)a_sw;
        *(short4*)(ab + frag_hi * 2)           = make_short4(hi[0], hi[1], hi[2], hi[3]);
        *(short4*)(ab + (frag_hi + 8192) * 2)  = make_short4(lo[0], lo[1], lo[2], lo[3]);  // +16384 B
        *(float4*)&eT[(size_t)c * DD + d0] = make_float4(v[0], v[1], v[2], v[3]);
    } else {
        const int c = (b - 128) * 256 + tid;
        float s = 0.f;
        #pragma unroll 8
        for (int d = 0; d < DD; d++) { float f = e[(size_t)d * KC + c]; s = fmaf(f, f, s); }
        s2g[c] = s;
    }
}

// ---------- main: transposed split-bf16 MFMA, global->reg streamed A ----------
__global__ __launch_bounds__(256) void k_main(const float* __restrict__ x,
                                              const unsigned short* __restrict__ a_sw,
                                              const float* __restrict__ s2g,
                                              const float* __restrict__ eT,
                                              int* __restrict__ idxg,
                                              float* __restrict__ out_q,
                                              double* __restrict__ loss_acc) {
    __shared__ float s2s[1024];      // 4 KB only

    const int tid = threadIdx.x;
    const int w = tid >> 6, lane = tid & 63;
    const int halfk = lane >> 5, col = lane & 31;
    const int row0 = blockIdx.x * 128;
    const int myrow = row0 + w * 32 + col;

    // ---- x fragments (persistent in registers): hi + lo, B-operand layout ----
    const float* xr = x + (size_t)myrow * DD;
    bf16x8 xh[8], xl[8];
    #pragma unroll
    for (int kd = 0; kd < 8; kd++) {
        const float* p = xr + kd * 16 + halfk * 8;
        float4 a = *(const float4*)p;
        float4 b = *(const float4*)(p + 4);
        float v[8] = {a.x, a.y, a.z, a.w, b.x, b.y, b.z, b.w};
        #pragma unroll
        for (int j = 0; j < 8; j++) {
            unsigned short h = f2bf(v[j]);
            xh[kd][j] = (short)h;
            xl[kd][j] = (short)f2bf(v[j] - bf2f(h));
        }
    }
    ((float4*)s2s)[tid] = ((const float4*)s2g)[tid];
    __syncthreads();

    // ---- A-fragment streaming: 4-stage register ring, depth-3 prefetch ----
    const char* ab = (const char*)a_sw;
    const int lane_b = lane * 16;
    bf16x8 fb[4][4];   // [stage][hi0,hi1,lo0,lo1]

    #define LDSTAGE(u_, st_) {                                              \
        int uu_ = (u_) < 127 ? (u_) : 127;                                  \
        const char* p_ = ab + (size_t)(uu_ >> 3) * 32768 + (uu_ & 7) * 2048 + lane_b; \
        fb[st_][0] = *(const bf16x8*)(p_);                                  \
        fb[st_][1] = *(const bf16x8*)(p_ + 1024);                           \
        fb[st_][2] = *(const bf16x8*)(p_ + 16384);                          \
        fb[st_][3] = *(const bf16x8*)(p_ + 17408);                          \
    }

    LDSTAGE(0, 0); LDSTAGE(1, 1); LDSTAGE(2, 2);

    float bv0 = 3.4e38f, bv1 = 3.4e38f;
    int bi0 = 0x7fffffff;

    #pragma unroll 1
    for (int ct = 0; ct < 16; ct++) {
        f32x16 acc0, acc1;
        #pragma unroll
        for (int r = 0; r < 16; r++) { acc0[r] = 0.f; acc1[r] = 0.f; }

        #pragma unroll
        for (int kd = 0; kd < 8; kd++) {
            const int u = ct * 8 + kd;
            const int s = u & 3;
            LDSTAGE(u + 3, (u + 3) & 3);
            // e_hi x x_hi ; e_lo x x_hi ; e_hi x x_lo  (e_hi frags reused in-register)
            acc0 = __builtin_amdgcn_mfma_f32_32x32x16_bf16(fb[s][0], xh[kd], acc0, 0, 0, 0);
            acc1 = __builtin_amdgcn_mfma_f32_32x32x16_bf16(fb[s][1], xh[kd], acc1, 0, 0, 0);
            acc0 = __builtin_amdgcn_mfma_f32_32x32x16_bf16(fb[s][2], xh[kd], acc0, 0, 0, 0);
            acc1 = __builtin_amdgcn_mfma_f32_32x32x16_bf16(fb[s][3], xh[kd], acc1, 0, 0, 0);
            acc0 = __builtin_amdgcn_mfma_f32_32x32x16_bf16(fb[s][0], xl[kd], acc0, 0, 0, 0);
            acc1 = __builtin_amdgcn_mfma_f32_32x32x16_bf16(fb[s][1], xl[kd], acc1, 0, 0, 0);
        }

        // fold distances: code = ct*64 + mt*32 + 4*halfk + g*8 + q  (reg r=g*4+q)
        int cb = ct * 64 + 4 * halfk;
        #pragma unroll
        for (int mt = 0; mt < 2; mt++) {
            #pragma unroll
            for (int g = 0; g < 4; g++) {
                float4 s2v = *(const float4*)&s2s[cb + mt * 32 + g * 8];
                const float* s2p = (const float*)&s2v;
                #pragma unroll
                for (int q = 0; q < 4; q++) {
                    int r = g * 4 + q;
                    float av = mt ? acc1[r] : acc0[r];
                    float dv = fmaf(-2.f, av, s2p[q]);
                    int c = cb + mt * 32 + g * 8 + q;
                    bool lt = dv < bv0;
                    bv1 = fminf(bv1, fmaxf(bv0, dv));
                    bv0 = fminf(bv0, dv);
                    bi0 = lt ? c : bi0;
                }
            }
        }
        __builtin_amdgcn_s_barrier();   // raw pacing barrier (no fence, no vmcnt drain)
    }

    // ---- merge the two k-halves (lanes l and l^32 share the same x-row) ----
    float u0 = __shfl_xor(bv0, 32, 64);
    float u1 = __shfl_xor(bv1, 32, 64);
    int   j0 = __shfl_xor(bi0, 32, 64);
    float v0, v1; int i0;
    if (u0 < bv0 || (u0 == bv0 && j0 < bi0)) { v0 = u0; i0 = j0; v1 = fminf(u1, bv0); }
    else                                     { v0 = bv0; i0 = bi0; v1 = fminf(bv1, u0); }

    int flag = (v1 - v0 < EPS_GAP) ? 1 : 0;
    int packed = i0 | (flag << 31);
    if (lane < 32) idxg[myrow] = packed;

    // ---- fused epilogue: gather quantized + loss for non-flagged rows ----
    float lsum = 0.f;
    #pragma unroll 8
    for (int r = 0; r < 32; r++) {
        int pk = __shfl(packed, r, 64);
        if (pk >= 0) {
            size_t grow = (size_t)row0 + w * 32 + r;
            float2 q  = *(const float2*)&eT[(size_t)pk * DD + lane * 2];
            float2 xv = *(const float2*)&x[grow * DD + lane * 2];
            *(float2*)&out_q[grow * DD + lane * 2] = q;
            float f0 = q.x - xv.x, f1 = q.y - xv.y;
            lsum = fmaf(f0, f0, fmaf(f1, f1, lsum));
        }
    }
    #pragma unroll
    for (int off = 32; off > 0; off >>= 1) lsum += __shfl_down(lsum, off, 64);
    if (lane == 0) atomicAdd(loss_acc, (double)lsum);
}

// ---------- fix: exact fp32 re-argmin + output for flagged (near-tie) rows ----------
__global__ __launch_bounds__(256) void k_fix(const float* __restrict__ x,
                                             const float* __restrict__ e,
                                             const float* __restrict__ eT,
                                             const float* __restrict__ s2g,
                                             const int* __restrict__ idxg,
                                             float* __restrict__ out_q,
                                             double* __restrict__ loss_acc) {
    __shared__ int anyf;
    __shared__ float xrow[DD];
    __shared__ float rv[256];
    __shared__ int   ri[256];
    __shared__ int   kml;
    __shared__ float wred[2];
    const int tid = threadIdx.x;
    const int row0 = blockIdx.x * 64;

    if (tid == 0) anyf = 0;
    __syncthreads();
    if (tid < 64) { if (idxg[row0 + tid] < 0) anyf = 1; }
    __syncthreads();
    if (!anyf) return;

    for (int r = 0; r < 64; r++) {
        int pkr = idxg[row0 + r];
        if (pkr >= 0) continue;   // uniform per block
        if (tid < 32) ((float4*)xrow)[tid] = ((const float4*)(x + (size_t)(row0 + r) * DD))[tid];
        __syncthreads();
        int c0 = tid * 4;
        float s0 = 0.f, s1 = 0.f, s2 = 0.f, s3 = 0.f;
        #pragma unroll 8
        for (int d = 0; d < DD; d++) {
            float xv = xrow[d];
            float4 ev = *(const float4*)(e + (size_t)d * KC + c0);
            s0 = fmaf(xv, ev.x, s0); s1 = fmaf(xv, ev.y, s1);
            s2 = fmaf(xv, ev.z, s2); s3 = fmaf(xv, ev.w, s3);
        }
        float dv0 = s2g[c0 + 0] - 2.f * s0;
        float dv1 = s2g[c0 + 1] - 2.f * s1;
        float dv2 = s2g[c0 + 2] - 2.f * s2;
        float dv3 = s2g[c0 + 3] - 2.f * s3;
        float bv = dv0; int bi = c0;
        if (dv1 < bv) { bv = dv1; bi = c0 + 1; }
        if (dv2 < bv) { bv = dv2; bi = c0 + 2; }
        if (dv3 < bv) { bv = dv3; bi = c0 + 3; }
        rv[tid] = bv; ri[tid] = bi;
        __syncthreads();
        if (tid == 0) {
            float b = rv[0]; int bidx = ri[0];
            for (int t = 1; t < 256; t++)
                if (rv[t] < b) { b = rv[t]; bidx = ri[t]; }
            kml = bidx;
        }
        __syncthreads();
        float ls = 0.f;
        if (tid < 128) {
            int km = kml;
            float q = eT[(size_t)km * DD + tid];
            float xv = xrow[tid];
            out_q[(size_t)(row0 + r) * DD + tid] = q;
            float f = q - xv;
            ls = f * f;
        }
        #pragma unroll
        for (int off = 32; off > 0; off >>= 1) ls += __shfl_down(ls, off, 64);
        if ((tid & 63) == 0 && tid < 128) wred[tid >> 6] = ls;
        __syncthreads();
        if (tid == 0) atomicAdd(loss_acc, (double)(wred[0] + wred[1]));
        __syncthreads();
    }
}

// ---------- codedist: second-smallest code-to-code distance -> scales ----------
// 4 codes/block from eT (LDS broadcast b128), each thread owns 4 contiguous j.
__global__ __launch_bounds__(256) void k_codedist(const float* __restrict__ e,
                                                  const float* __restrict__ eT,
                                                  const float* __restrict__ s2g,
                                                  float* __restrict__ out_scales) {
    __shared__ float ek[4][DD];
    __shared__ float red0[4][256];
    __shared__ float red1[4][256];
    __shared__ float sc[4];
    const int tid = threadIdx.x;
    const int kb = blockIdx.x * 4;

    if (tid < 128) {
        int ki = tid >> 5, t = tid & 31;
        float4 v = *(const float4*)&eT[(size_t)(kb + ki) * DD + t * 4];
        *(float4*)&ek[ki][t * 4] = v;
    }
    __syncthreads();

    const int j0 = tid * 4;
    float s[4][4];
    #pragma unroll
    for (int a = 0; a < 4; a++)
        #pragma unroll
        for (int b = 0; b < 4; b++) s[a][b] = 0.f;

    #pragma unroll 1
    for (int dc = 0; dc < 32; dc++) {
        int d0 = dc * 4;
        float4 ev[4], ekv[4];
        #pragma unroll
        for (int dd = 0; dd < 4; dd++)
            ev[dd] = *(const float4*)&e[(size_t)(d0 + dd) * KC + j0];
        #pragma unroll
        for (int ki = 0; ki < 4; ki++)
            ekv[ki] = *(const float4*)&ek[ki][d0];
        #pragma unroll
        for (int ki = 0; ki < 4; ki++) {
            const float* ekp = (const float*)&ekv[ki];
            #pragma unroll
            for (int dd = 0; dd < 4; dd++) {
                const float* evp = (const float*)&ev[dd];
                float ekd = ekp[dd];
                s[ki][0] = fmaf(ekd, evp[0], s[ki][0]);
                s[ki][1] = fmaf(ekd, evp[1], s[ki][1]);
                s[ki][2] = fmaf(ekd, evp[2], s[ki][2]);
                s[ki][3] = fmaf(ekd, evp[3], s[ki][3]);
            }
        }
    }

    float4 s2jv = *(const float4*)&s2g[j0];
    const float* s2jp = (const float*)&s2jv;
    float m0[4] = {3.4e38f, 3.4e38f, 3.4e38f, 3.4e38f};
    float m1[4] = {3.4e38f, 3.4e38f, 3.4e38f, 3.4e38f};
    #pragma unroll
    for (int ki = 0; ki < 4; ki++) {
        float s2k = s2g[kb + ki];
        #pragma unroll
        for (int jj = 0; jj < 4; jj++) {
            float dd = (s2k + s2jp[jj]) - 2.f * s[ki][jj];
            if (dd < m0[ki]) { m1[ki] = m0[ki]; m0[ki] = dd; }
            else if (dd < m1[ki]) m1[ki] = dd;
        }
    }
    #pragma unroll
    for (int i = 0; i < 4; i++) { red0[i][tid] = m0[i]; red1[i][tid] = m1[i]; }
    __syncthreads();
    if (tid < 4) {
        float a0 = 3.4e38f, a1 = 3.4e38f;
        for (int t = 0; t < 256; t++) {
            float v0 = red0[tid][t], v1 = red1[tid][t];
            if (v0 < a0) { a1 = fminf(a0, v1); a0 = v0; }
            else a1 = fminf(a1, v0);
        }
        sc[tid] = a1 * (1.0f / 64.0f);   // second_smallest / (D/2)
    }
    __syncthreads();
    if (tid < 128) {
        #pragma unroll
        for (int i = 0; i < 4; i++)
            out_scales[(size_t)(kb + i) * DD + tid] = sc[i];
    }
}

// ---------- finalize ----------
__global__ void k_finalize(const double* __restrict__ loss_acc,
                           float* __restrict__ out_loss) {
    double m = loss_acc[0] / 4194304.0;
    out_loss[0] = (float)(0.25 * m + m);
}

extern "C" void kernel_launch(void* const* d_in, const int* in_sizes, int n_in,
                              void* d_out, int out_size, void* d_ws, size_t ws_size,
                              hipStream_t stream) {
    const float* x = (const float*)d_in[0];
    const float* e = (const float*)d_in[1];
    float* out_q      = (float*)d_out;
    float* out_loss   = out_q + (size_t)NROWS * DD;
    float* out_scales = out_loss + 1;

    char* ws = (char*)d_ws;
    double* loss_acc       = (double*)(ws + 0);
    float*  s2g            = (float*)(ws + 1024);
    int*    idxg           = (int*)(ws + 8192);
    float*  eT             = (float*)(ws + 139264);
    unsigned short* a_sw   = (unsigned short*)(ws + 663552);

    hipMemsetAsync(ws, 0, 16, stream);
    k_prep<<<132, 256, 0, stream>>>(e, a_sw, eT, s2g);
    k_main<<<NROWS / 128, 256, 0, stream>>>(x, a_sw, s2g, eT, idxg, out_q, loss_acc);
    k_codedist<<<KC / 4, 256, 0, stream>>>(e, eT, s2g, out_scales);
    k_fix<<<NROWS / 64, 256, 0, stream>>>(x, e, eT, s2g, idxg, out_q, loss_acc);
    k_finalize<<<1, 1, 0, stream>>>(loss_acc, out_loss);
}

// Round 5
// 208.577 us; speedup vs baseline: 1.4248x; 1.0605x over previous
//
#include <hip/hip_runtime.h>

typedef __attribute__((ext_vector_type(8))) short bf16x8;
typedef __attribute__((ext_vector_type(16))) float f32x16;

#define NROWS 32768
#define KC 1024
#define DD 128
#define EPS_GAP 1e-3f
#define FLT_BIG 3.4e38f

typedef const unsigned int __attribute__((address_space(1)))* gp1_t;
typedef unsigned int __attribute__((address_space(3)))* lp3_t;

__device__ __forceinline__ unsigned short f2bf(float f) {
    unsigned u = __float_as_uint(f);
    unsigned r = u + 0x7FFFu + ((u >> 16) & 1u);
    return (unsigned short)(r >> 16);
}
__device__ __forceinline__ float bf2f(unsigned short h) {
    return __uint_as_float(((unsigned)h) << 16);
}

// ================= combined prep + s2 + codedist =================
// blocks 0..127   : e -> bf16 hi/lo A-frags (2 tiles of (ct,kd) each) + eT
// blocks 128..131 : s2[c]
// blocks 132..643 : code-to-code second-smallest distance -> scales (2 codes each)
// a_sw layout (shorts): frag(ct 0..31, kd 0..7, term 0..1) = ((ct*8+kd)*2+term)*512
//   lane l holds A[m=l&31][k=(l>>5)*8+j] for code ct*32+m, d = kd*16+(l>>5)*8+j.
__global__ __launch_bounds__(256) void k_prep_cd(const float* __restrict__ e,
                                                 unsigned short* __restrict__ a_sw,
                                                 float* __restrict__ eT,
                                                 float* __restrict__ s2g,
                                                 float* __restrict__ out_scales) {
    const int b = blockIdx.x, tid = threadIdx.x;
    if (b < 128) {
        const int t = b * 2 + (tid >> 7);     // tile 0..255
        const int ct = t >> 3, kd = t & 7;
        const int tt = tid & 127;
        const int m = tt & 31, dg = tt >> 5;
        const int c = ct * 32 + m;
        const int d0 = kd * 16 + dg * 4;
        float v[4]; short hi[4], lo[4];
        #pragma unroll
        for (int jj = 0; jj < 4; jj++) {
            float f = e[(size_t)(d0 + jj) * KC + c];
            v[jj] = f;
            unsigned short hh = f2bf(f);
            hi[jj] = (short)hh;
            lo[jj] = (short)f2bf(f - bf2f(hh));
        }
        const int h = dg >> 1, jb = (dg & 1) * 4;
        size_t base = ((size_t)(ct * 8 + kd) * 2) * 512 + (h * 32 + m) * 8 + jb;
        *(short4*)&a_sw[base]       = make_short4(hi[0], hi[1], hi[2], hi[3]);
        *(short4*)&a_sw[base + 512] = make_short4(lo[0], lo[1], lo[2], lo[3]);
        *(float4*)&eT[(size_t)c * DD + d0] = make_float4(v[0], v[1], v[2], v[3]);
    } else if (b < 132) {
        const int c = (b - 128) * 256 + tid;
        float s = 0.f;
        #pragma unroll 8
        for (int d = 0; d < DD; d++) { float f = e[(size_t)d * KC + c]; s = fmaf(f, f, s); }
        s2g[c] = s;
    } else {
        // ---- codedist: 2 codes per block, diff-square (no s2 dependency) ----
        __shared__ float ek[2][DD];
        __shared__ float r0w[2][4], r1w[2][4];
        __shared__ float scsh[2];
        const int kb = (b - 132) * 2;
        { int ki = tid >> 7, d = tid & 127; ek[ki][d] = e[(size_t)d * KC + kb + ki]; }
        __syncthreads();
        const int j0 = tid * 4;
        float da[2][4];
        #pragma unroll
        for (int ki = 0; ki < 2; ki++)
            #pragma unroll
            for (int jj = 0; jj < 4; jj++) da[ki][jj] = 0.f;
        #pragma unroll 2
        for (int dc = 0; dc < 32; dc++) {
            int d0 = dc * 4;
            float4 ev[4];
            #pragma unroll
            for (int dd = 0; dd < 4; dd++)
                ev[dd] = *(const float4*)&e[(size_t)(d0 + dd) * KC + j0];
            float4 ek0 = *(const float4*)&ek[0][d0];
            float4 ek1 = *(const float4*)&ek[1][d0];
            const float* e0 = (const float*)&ek0;
            const float* e1 = (const float*)&ek1;
            #pragma unroll
            for (int dd = 0; dd < 4; dd++) {
                const float* evp = (const float*)&ev[dd];
                #pragma unroll
                for (int jj = 0; jj < 4; jj++) {
                    float t0 = e0[dd] - evp[jj];
                    float t1 = e1[dd] - evp[jj];
                    da[0][jj] = fmaf(t0, t0, da[0][jj]);
                    da[1][jj] = fmaf(t1, t1, da[1][jj]);
                }
            }
        }
        float m0[2] = {FLT_BIG, FLT_BIG}, m1[2] = {FLT_BIG, FLT_BIG};
        #pragma unroll
        for (int ki = 0; ki < 2; ki++)
            #pragma unroll
            for (int jj = 0; jj < 4; jj++) {
                float dd = da[ki][jj];
                if (dd < m0[ki]) { m1[ki] = m0[ki]; m0[ki] = dd; }
                else if (dd < m1[ki]) m1[ki] = dd;
            }
        #pragma unroll
        for (int msk = 1; msk < 64; msk <<= 1) {
            #pragma unroll
            for (int ki = 0; ki < 2; ki++) {
                float u0 = __shfl_xor(m0[ki], msk, 64);
                float u1 = __shfl_xor(m1[ki], msk, 64);
                if (u0 < m0[ki]) { m1[ki] = fminf(m0[ki], u1); m0[ki] = u0; }
                else             { m1[ki] = fminf(m1[ki], u0); }
            }
        }
        const int w = tid >> 6;
        if ((tid & 63) == 0) {
            r0w[0][w] = m0[0]; r1w[0][w] = m1[0];
            r0w[1][w] = m0[1]; r1w[1][w] = m1[1];
        }
        __syncthreads();
        if (tid < 2) {
            float a0 = FLT_BIG, a1 = FLT_BIG;
            #pragma unroll
            for (int ww = 0; ww < 4; ww++) {
                float v0 = r0w[tid][ww], v1 = r1w[tid][ww];
                if (v0 < a0) { a1 = fminf(a0, v1); a0 = v0; }
                else a1 = fminf(a1, v0);
            }
            scsh[tid] = a1 * (1.0f / 64.0f);   // second_smallest / (D/2)
        }
        __syncthreads();
        if (tid < 128) {
            out_scales[(size_t)kb * DD + tid]       = scsh[0];
            out_scales[(size_t)(kb + 1) * DD + tid] = scsh[1];
        }
    }
}

// ================= main: 128 rows x 128 codes per block =================
// grid 2048: g = blockIdx>>8 (code group), rg = blockIdx&255 (row group).
// LDS: one-time stage of g's 64 KB frag chunk; zero barriers in main loop.
__global__ __launch_bounds__(256, 2) void k_main(const float* __restrict__ x,
                                                 const unsigned short* __restrict__ a_sw,
                                                 const float* __restrict__ s2g,
                                                 float* __restrict__ pv0,
                                                 float* __restrict__ pv1,
                                                 int* __restrict__ pi0) {
    __shared__ short es[32768];     // 64 KB
    __shared__ float s2s[128];

    const int tid = threadIdx.x;
    const int w = tid >> 6, lane = tid & 63;
    const int halfk = lane >> 5, col = lane & 31;
    const int g = blockIdx.x >> 8;
    const int rg = blockIdx.x & 255;
    const int myrow = rg * 128 + w * 32 + col;

    // stage A-chunk (64 KB contiguous) into LDS
    {
        const char* src = (const char*)a_sw + (size_t)g * 65536;
        char* dst = (char*)es;
        #pragma unroll
        for (int it = 0; it < 16; it++) {
            int off = (it * 256 + tid) * 16;
            __builtin_amdgcn_global_load_lds((gp1_t)(const void*)(src + off),
                                             (lp3_t)(void*)(dst + off), 16, 0, 0);
        }
    }
    if (tid < 128) s2s[tid] = s2g[g * 128 + tid];

    // x fragments resident: hi + lo, B-operand layout (overlaps with staging)
    const float* xr = x + (size_t)myrow * DD;
    bf16x8 xh[8], xl[8];
    #pragma unroll
    for (int kd = 0; kd < 8; kd++) {
        const float* p = xr + kd * 16 + halfk * 8;
        float4 a = *(const float4*)p;
        float4 b = *(const float4*)(p + 4);
        float v[8] = {a.x, a.y, a.z, a.w, b.x, b.y, b.z, b.w};
        #pragma unroll
        for (int j = 0; j < 8; j++) {
            unsigned short h = f2bf(v[j]);
            xh[kd][j] = (short)h;
            xl[kd][j] = (short)f2bf(v[j] - bf2f(h));
        }
    }
    __syncthreads();   // one drain for the whole kernel

    float bv0 = FLT_BIG, bv1 = FLT_BIG;
    int bi0 = 0x7fffffff;

    #pragma unroll 1
    for (int ct = 0; ct < 4; ct++) {
        f32x16 accA, accB, accC;
        #pragma unroll
        for (int r = 0; r < 16; r++) { accA[r] = 0.f; accB[r] = 0.f; accC[r] = 0.f; }

        #pragma unroll
        for (int kd = 0; kd < 8; kd++) {
            const short* fp = &es[((ct * 8 + kd) * 2) * 512 + lane * 8];
            bf16x8 ahi = *(const bf16x8*)fp;
            bf16x8 alo = *(const bf16x8*)(fp + 512);
            accA = __builtin_amdgcn_mfma_f32_32x32x16_bf16(ahi, xh[kd], accA, 0, 0, 0);
            accB = __builtin_amdgcn_mfma_f32_32x32x16_bf16(alo, xh[kd], accB, 0, 0, 0);
            accC = __builtin_amdgcn_mfma_f32_32x32x16_bf16(ahi, xl[kd], accC, 0, 0, 0);
        }

        // fold: local code cl = ct*32 + 4*halfk + g8*8 + q  (reg r = g8*4+q)
        int clb = ct * 32 + 4 * halfk;
        #pragma unroll
        for (int g8 = 0; g8 < 4; g8++) {
            float4 s2v = *(const float4*)&s2s[clb + g8 * 8];
            const float* s2p = (const float*)&s2v;
            #pragma unroll
            for (int q = 0; q < 4; q++) {
                int r = g8 * 4 + q;
                float sim = (accA[r] + accB[r]) + accC[r];
                float dv = fmaf(-2.f, sim, s2p[q]);
                int ci = g * 128 + clb + g8 * 8 + q;
                bool lt = dv < bv0;
                bv1 = fminf(bv1, fmaxf(bv0, dv));
                bv0 = fminf(bv0, dv);
                bi0 = lt ? ci : bi0;
            }
        }
    }

    // merge the two k-halves (lanes l, l^32 share the same x-row)
    float u0 = __shfl_xor(bv0, 32, 64);
    float u1 = __shfl_xor(bv1, 32, 64);
    int   j0 = __shfl_xor(bi0, 32, 64);
    float v0, v1; int i0;
    if (u0 < bv0 || (u0 == bv0 && j0 < bi0)) { v0 = u0; i0 = j0; v1 = fminf(u1, bv0); }
    else                                     { v0 = bv0; i0 = bi0; v1 = fminf(bv1, u0); }

    if (lane < 32) {
        size_t o = (size_t)g * NROWS + myrow;
        pv0[o] = v0; pv1[o] = v1; pi0[o] = i0;
    }
}

// ================= out: merge 8 partials/row, fallback, gather, loss =================
__global__ __launch_bounds__(256) void k_out(const float* __restrict__ x,
                                             const float* __restrict__ e,
                                             const float* __restrict__ eT,
                                             const float* __restrict__ s2g,
                                             const float* __restrict__ pv0,
                                             const float* __restrict__ pv1,
                                             const int* __restrict__ pi0,
                                             float* __restrict__ out_q,
                                             double* __restrict__ loss_acc) {
    __shared__ int   kml[256];
    __shared__ int   flist[256];
    __shared__ int   nflag;
    __shared__ float xrow[DD];
    __shared__ float rv[256];
    __shared__ int   ri[256];
    __shared__ int   kfix;
    __shared__ float wsum[4];
    const int tid = threadIdx.x;
    const int w = tid >> 6, lane = tid & 63;
    const int row0 = blockIdx.x * 256;

    if (tid == 0) nflag = 0;
    __syncthreads();

    // phase 1: merge 8 code-group candidates per row (ascending g => index order ok)
    {
        const int row = row0 + tid;
        float v0 = FLT_BIG, v1 = FLT_BIG; int i0 = 0x7fffffff;
        #pragma unroll
        for (int g = 0; g < 8; g++) {
            size_t o = (size_t)g * NROWS + row;
            float u0 = pv0[o], u1 = pv1[o]; int j0 = pi0[o];
            if (u0 < v0 || (u0 == v0 && j0 < i0)) { v1 = fminf(v0, u1); v0 = u0; i0 = j0; }
            else v1 = fminf(v1, u0);
        }
        kml[tid] = i0;
        if (v1 - v0 < EPS_GAP) { int s = atomicAdd(&nflag, 1); flist[s] = tid; }
    }
    __syncthreads();

    // phase 2: exact fp32 re-argmin for flagged rows (rare)
    for (int fi = 0; fi < nflag; fi++) {
        int r = flist[fi];
        if (tid < 32) ((float4*)xrow)[tid] = ((const float4*)(x + (size_t)(row0 + r) * DD))[tid];
        __syncthreads();
        int c0 = tid * 4;
        float s0 = 0.f, s1 = 0.f, s2 = 0.f, s3 = 0.f;
        #pragma unroll 8
        for (int d = 0; d < DD; d++) {
            float xv = xrow[d];
            float4 ev = *(const float4*)(e + (size_t)d * KC + c0);
            s0 = fmaf(xv, ev.x, s0); s1 = fmaf(xv, ev.y, s1);
            s2 = fmaf(xv, ev.z, s2); s3 = fmaf(xv, ev.w, s3);
        }
        float dv0 = s2g[c0 + 0] - 2.f * s0;
        float dv1 = s2g[c0 + 1] - 2.f * s1;
        float dv2 = s2g[c0 + 2] - 2.f * s2;
        float dv3 = s2g[c0 + 3] - 2.f * s3;
        float bv = dv0; int bi = c0;
        if (dv1 < bv) { bv = dv1; bi = c0 + 1; }
        if (dv2 < bv) { bv = dv2; bi = c0 + 2; }
        if (dv3 < bv) { bv = dv3; bi = c0 + 3; }
        rv[tid] = bv; ri[tid] = bi;
        __syncthreads();
        if (tid == 0) {
            float b = rv[0]; int bidx = ri[0];
            for (int t = 1; t < 256; t++)
                if (rv[t] < b) { b = rv[t]; bidx = ri[t]; }
            kfix = bidx;
        }
        __syncthreads();
        if (tid == 0) kml[r] = kfix;
        __syncthreads();
    }

    // phase 3: gather quantized + loss (wave w -> rows w*64..w*64+63)
    float lsum = 0.f;
    #pragma unroll 4
    for (int rr = 0; rr < 64; rr++) {
        int r = w * 64 + rr;
        int km = kml[r];
        size_t grow = (size_t)row0 + r;
        float2 q  = *(const float2*)&eT[(size_t)km * DD + lane * 2];
        float2 xv = *(const float2*)&x[grow * DD + lane * 2];
        *(float2*)&out_q[grow * DD + lane * 2] = q;
        float f0 = q.x - xv.x, f1 = q.y - xv.y;
        lsum = fmaf(f0, f0, fmaf(f1, f1, lsum));
    }
    #pragma unroll
    for (int off = 32; off > 0; off >>= 1) lsum += __shfl_down(lsum, off, 64);
    if (lane == 0) wsum[w] = lsum;
    __syncthreads();
    if (tid == 0)
        atomicAdd(loss_acc, (double)((wsum[0] + wsum[1]) + (wsum[2] + wsum[3])));
}

// ================= finalize =================
__global__ void k_finalize(const double* __restrict__ loss_acc,
                           float* __restrict__ out_loss) {
    double m = loss_acc[0] / 4194304.0;
    out_loss[0] = (float)(0.25 * m + m);
}

extern "C" void kernel_launch(void* const* d_in, const int* in_sizes, int n_in,
                              void* d_out, int out_size, void* d_ws, size_t ws_size,
                              hipStream_t stream) {
    const float* x = (const float*)d_in[0];
    const float* e = (const float*)d_in[1];
    float* out_q      = (float*)d_out;
    float* out_loss   = out_q + (size_t)NROWS * DD;
    float* out_scales = out_loss + 1;

    char* ws = (char*)d_ws;
    double* loss_acc     = (double*)(ws + 0);
    float*  s2g          = (float*)(ws + 1024);
    float*  pv0          = (float*)(ws + 16384);
    float*  pv1          = (float*)(ws + 1064960);
    int*    pi0          = (int*)(ws + 2113536);
    float*  eT           = (float*)(ws + 3162112);
    unsigned short* a_sw = (unsigned short*)(ws + 3686400);

    hipMemsetAsync(ws, 0, 16, stream);
    k_prep_cd<<<644, 256, 0, stream>>>(e, a_sw, eT, s2g, out_scales);
    k_main<<<2048, 256, 0, stream>>>(x, a_sw, s2g, pv0, pv1, pi0);
    k_out<<<NROWS / 256, 256, 0, stream>>>(x, e, eT, s2g, pv0, pv1, pi0, out_q, loss_acc);
    k_finalize<<<1, 1, 0, stream>>>(loss_acc, out_loss);
}

// Round 6
// 177.768 us; speedup vs baseline: 1.6718x; 1.1733x over previous
//
#include <hip/hip_runtime.h>

typedef __attribute__((ext_vector_type(8))) short bf16x8;
typedef __attribute__((ext_vector_type(16))) float f32x16;

#define NROWS 32768
#define KC 1024
#define DD 128
#define EPS_GAP 1e-3f
#define FLT_BIG 3.4e38f

typedef const unsigned int __attribute__((address_space(1)))* gp1_t;
typedef unsigned int __attribute__((address_space(3)))* lp3_t;

__device__ __forceinline__ unsigned short f2bf(float f) {
    unsigned u = __float_as_uint(f);
    unsigned r = u + 0x7FFFu + ((u >> 16) & 1u);
    return (unsigned short)(r >> 16);
}
__device__ __forceinline__ float bf2f(unsigned short h) {
    return __uint_as_float(((unsigned)h) << 16);
}

// ================= combined prep + s2 + codedist =================
__global__ __launch_bounds__(256) void k_prep_cd(const float* __restrict__ e,
                                                 unsigned short* __restrict__ a_sw,
                                                 float* __restrict__ eT,
                                                 float* __restrict__ s2g,
                                                 float* __restrict__ out_scales) {
    const int b = blockIdx.x, tid = threadIdx.x;
    if (b < 128) {
        const int t = b * 2 + (tid >> 7);     // tile 0..255
        const int ct = t >> 3, kd = t & 7;
        const int tt = tid & 127;
        const int m = tt & 31, dg = tt >> 5;
        const int c = ct * 32 + m;
        const int d0 = kd * 16 + dg * 4;
        float v[4]; short hi[4], lo[4];
        #pragma unroll
        for (int jj = 0; jj < 4; jj++) {
            float f = e[(size_t)(d0 + jj) * KC + c];
            v[jj] = f;
            unsigned short hh = f2bf(f);
            hi[jj] = (short)hh;
            lo[jj] = (short)f2bf(f - bf2f(hh));
        }
        const int h = dg >> 1, jb = (dg & 1) * 4;
        size_t base = ((size_t)(ct * 8 + kd) * 2) * 512 + (h * 32 + m) * 8 + jb;
        *(short4*)&a_sw[base]       = make_short4(hi[0], hi[1], hi[2], hi[3]);
        *(short4*)&a_sw[base + 512] = make_short4(lo[0], lo[1], lo[2], lo[3]);
        *(float4*)&eT[(size_t)c * DD + d0] = make_float4(v[0], v[1], v[2], v[3]);
    } else if (b < 132) {
        const int c = (b - 128) * 256 + tid;
        float s = 0.f;
        #pragma unroll 8
        for (int d = 0; d < DD; d++) { float f = e[(size_t)d * KC + c]; s = fmaf(f, f, s); }
        s2g[c] = s;
    } else {
        // ---- codedist: 2 codes per block, diff-square (no s2 dependency) ----
        __shared__ float ek[2][DD];
        __shared__ float r0w[2][4], r1w[2][4];
        __shared__ float scsh[2];
        const int kb = (b - 132) * 2;
        { int ki = tid >> 7, d = tid & 127; ek[ki][d] = e[(size_t)d * KC + kb + ki]; }
        __syncthreads();
        const int j0 = tid * 4;
        float da[2][4];
        #pragma unroll
        for (int ki = 0; ki < 2; ki++)
            #pragma unroll
            for (int jj = 0; jj < 4; jj++) da[ki][jj] = 0.f;
        #pragma unroll 2
        for (int dc = 0; dc < 32; dc++) {
            int d0 = dc * 4;
            float4 ev[4];
            #pragma unroll
            for (int dd = 0; dd < 4; dd++)
                ev[dd] = *(const float4*)&e[(size_t)(d0 + dd) * KC + j0];
            float4 ek0 = *(const float4*)&ek[0][d0];
            float4 ek1 = *(const float4*)&ek[1][d0];
            const float* e0 = (const float*)&ek0;
            const float* e1 = (const float*)&ek1;
            #pragma unroll
            for (int dd = 0; dd < 4; dd++) {
                const float* evp = (const float*)&ev[dd];
                #pragma unroll
                for (int jj = 0; jj < 4; jj++) {
                    float t0 = e0[dd] - evp[jj];
                    float t1 = e1[dd] - evp[jj];
                    da[0][jj] = fmaf(t0, t0, da[0][jj]);
                    da[1][jj] = fmaf(t1, t1, da[1][jj]);
                }
            }
        }
        float m0[2] = {FLT_BIG, FLT_BIG}, m1[2] = {FLT_BIG, FLT_BIG};
        #pragma unroll
        for (int ki = 0; ki < 2; ki++)
            #pragma unroll
            for (int jj = 0; jj < 4; jj++) {
                float dd = da[ki][jj];
                if (dd < m0[ki]) { m1[ki] = m0[ki]; m0[ki] = dd; }
                else if (dd < m1[ki]) m1[ki] = dd;
            }
        #pragma unroll
        for (int msk = 1; msk < 64; msk <<= 1) {
            #pragma unroll
            for (int ki = 0; ki < 2; ki++) {
                float u0 = __shfl_xor(m0[ki], msk, 64);
                float u1 = __shfl_xor(m1[ki], msk, 64);
                if (u0 < m0[ki]) { m1[ki] = fminf(m0[ki], u1); m0[ki] = u0; }
                else             { m1[ki] = fminf(m1[ki], u0); }
            }
        }
        const int w = tid >> 6;
        if ((tid & 63) == 0) {
            r0w[0][w] = m0[0]; r1w[0][w] = m1[0];
            r0w[1][w] = m0[1]; r1w[1][w] = m1[1];
        }
        __syncthreads();
        if (tid < 2) {
            float a0 = FLT_BIG, a1 = FLT_BIG;
            #pragma unroll
            for (int ww = 0; ww < 4; ww++) {
                float v0 = r0w[tid][ww], v1 = r1w[tid][ww];
                if (v0 < a0) { a1 = fminf(a0, v1); a0 = v0; }
                else a1 = fminf(a1, v0);
            }
            scsh[tid] = a1 * (1.0f / 64.0f);   // second_smallest / (D/2)
        }
        __syncthreads();
        if (tid < 128) {
            out_scales[(size_t)kb * DD + tid]       = scsh[0];
            out_scales[(size_t)(kb + 1) * DD + tid] = scsh[1];
        }
    }
}

// ================= main: 128 rows x 128 codes per block =================
__global__ __launch_bounds__(256, 2) void k_main(const float* __restrict__ x,
                                                 const unsigned short* __restrict__ a_sw,
                                                 const float* __restrict__ s2g,
                                                 float* __restrict__ pv0,
                                                 float* __restrict__ pv1,
                                                 int* __restrict__ pi0) {
    __shared__ short es[32768];     // 64 KB
    __shared__ float s2s[128];

    const int tid = threadIdx.x;
    const int w = tid >> 6, lane = tid & 63;
    const int halfk = lane >> 5, col = lane & 31;
    const int g = blockIdx.x >> 8;
    const int rg = blockIdx.x & 255;
    const int myrow = rg * 128 + w * 32 + col;

    {
        const char* src = (const char*)a_sw + (size_t)g * 65536;
        char* dst = (char*)es;
        #pragma unroll
        for (int it = 0; it < 16; it++) {
            int off = (it * 256 + tid) * 16;
            __builtin_amdgcn_global_load_lds((gp1_t)(const void*)(src + off),
                                             (lp3_t)(void*)(dst + off), 16, 0, 0);
        }
    }
    if (tid < 128) s2s[tid] = s2g[g * 128 + tid];

    const float* xr = x + (size_t)myrow * DD;
    bf16x8 xh[8], xl[8];
    #pragma unroll
    for (int kd = 0; kd < 8; kd++) {
        const float* p = xr + kd * 16 + halfk * 8;
        float4 a = *(const float4*)p;
        float4 b = *(const float4*)(p + 4);
        float v[8] = {a.x, a.y, a.z, a.w, b.x, b.y, b.z, b.w};
        #pragma unroll
        for (int j = 0; j < 8; j++) {
            unsigned short h = f2bf(v[j]);
            xh[kd][j] = (short)h;
            xl[kd][j] = (short)f2bf(v[j] - bf2f(h));
        }
    }
    __syncthreads();   // one drain for the whole kernel

    float bv0 = FLT_BIG, bv1 = FLT_BIG;
    int bi0 = 0x7fffffff;

    #pragma unroll 1
    for (int ct = 0; ct < 4; ct++) {
        f32x16 accA, accB, accC;
        #pragma unroll
        for (int r = 0; r < 16; r++) { accA[r] = 0.f; accB[r] = 0.f; accC[r] = 0.f; }

        #pragma unroll
        for (int kd = 0; kd < 8; kd++) {
            const short* fp = &es[((ct * 8 + kd) * 2) * 512 + lane * 8];
            bf16x8 ahi = *(const bf16x8*)fp;
            bf16x8 alo = *(const bf16x8*)(fp + 512);
            accA = __builtin_amdgcn_mfma_f32_32x32x16_bf16(ahi, xh[kd], accA, 0, 0, 0);
            accB = __builtin_amdgcn_mfma_f32_32x32x16_bf16(alo, xh[kd], accB, 0, 0, 0);
            accC = __builtin_amdgcn_mfma_f32_32x32x16_bf16(ahi, xl[kd], accC, 0, 0, 0);
        }

        int clb = ct * 32 + 4 * halfk;
        #pragma unroll
        for (int g8 = 0; g8 < 4; g8++) {
            float4 s2v = *(const float4*)&s2s[clb + g8 * 8];
            const float* s2p = (const float*)&s2v;
            #pragma unroll
            for (int q = 0; q < 4; q++) {
                int r = g8 * 4 + q;
                float sim = (accA[r] + accB[r]) + accC[r];
                float dv = fmaf(-2.f, sim, s2p[q]);
                int ci = g * 128 + clb + g8 * 8 + q;
                bool lt = dv < bv0;
                bv1 = fminf(bv1, fmaxf(bv0, dv));
                bv0 = fminf(bv0, dv);
                bi0 = lt ? ci : bi0;
            }
        }
    }

    float u0 = __shfl_xor(bv0, 32, 64);
    float u1 = __shfl_xor(bv1, 32, 64);
    int   j0 = __shfl_xor(bi0, 32, 64);
    float v0, v1; int i0;
    if (u0 < bv0 || (u0 == bv0 && j0 < bi0)) { v0 = u0; i0 = j0; v1 = fminf(u1, bv0); }
    else                                     { v0 = bv0; i0 = bi0; v1 = fminf(bv1, u0); }

    if (lane < 32) {
        size_t o = (size_t)g * NROWS + myrow;
        pv0[o] = v0; pv1[o] = v1; pi0[o] = i0;
    }
}

// ================= merge: 8 partials/row -> kml (+flag list) =================
__global__ __launch_bounds__(256) void k_merge(const float* __restrict__ pv0,
                                               const float* __restrict__ pv1,
                                               const int* __restrict__ pi0,
                                               int* __restrict__ kml,
                                               int* __restrict__ flist,
                                               int* __restrict__ nflag_g) {
    const int row = blockIdx.x * 256 + threadIdx.x;
    float v0 = FLT_BIG, v1 = FLT_BIG; int i0 = 0x7fffffff;
    #pragma unroll
    for (int g = 0; g < 8; g++) {
        size_t o = (size_t)g * NROWS + row;
        float u0 = pv0[o], u1 = pv1[o]; int j0 = pi0[o];
        if (u0 < v0 || (u0 == v0 && j0 < i0)) { v1 = fminf(v0, u1); v0 = u0; i0 = j0; }
        else v1 = fminf(v1, u0);
    }
    int flag = (v1 - v0 < EPS_GAP) ? 1 : 0;
    kml[row] = i0 | (flag << 31);
    if (flag) { int s = atomicAdd(nflag_g, 1); flist[s] = row; }
}

// ================= gather: element-parallel quantized write + loss =================
__global__ __launch_bounds__(256) void k_gather(const float* __restrict__ x,
                                                const float* __restrict__ eT,
                                                const int* __restrict__ kml,
                                                float* __restrict__ out_q,
                                                double* __restrict__ loss_acc) {
    __shared__ float wsum[4];
    const int tid = threadIdx.x;
    const int w = tid >> 6, lane = tid & 63;
    const int row = blockIdx.x * 32 + (tid >> 3);   // 32 rows/block, 8 threads/row
    const int seg = (tid & 7) * 16;                 // 16 consecutive floats each

    int pk = kml[row];
    float lsum = 0.f;
    if (pk >= 0) {
        const float* qp = eT + (size_t)pk * DD + seg;
        const float* xp = x + (size_t)row * DD + seg;
        float* op = out_q + (size_t)row * DD + seg;
        #pragma unroll
        for (int i = 0; i < 4; i++) {
            float4 q  = *(const float4*)(qp + i * 4);
            float4 xv = *(const float4*)(xp + i * 4);
            *(float4*)(op + i * 4) = q;
            float f0 = q.x - xv.x, f1 = q.y - xv.y;
            float f2 = q.z - xv.z, f3 = q.w - xv.w;
            lsum = fmaf(f0, f0, lsum); lsum = fmaf(f1, f1, lsum);
            lsum = fmaf(f2, f2, lsum); lsum = fmaf(f3, f3, lsum);
        }
    }
    #pragma unroll
    for (int off = 32; off > 0; off >>= 1) lsum += __shfl_down(lsum, off, 64);
    if (lane == 0) wsum[w] = lsum;
    __syncthreads();
    if (tid == 0)
        atomicAdd(loss_acc, (double)((wsum[0] + wsum[1]) + (wsum[2] + wsum[3])));
}

// ================= fix: exact fp32 re-argmin for flagged rows =================
__global__ __launch_bounds__(256) void k_fix(const float* __restrict__ x,
                                             const float* __restrict__ e,
                                             const float* __restrict__ eT,
                                             const float* __restrict__ s2g,
                                             const int* __restrict__ flist,
                                             const int* __restrict__ nflag_g,
                                             float* __restrict__ out_q,
                                             double* __restrict__ loss_acc) {
    __shared__ float xrow[DD];
    __shared__ float rv[256];
    __shared__ int   ri[256];
    __shared__ int   kfix;
    __shared__ float wred[2];
    const int tid = threadIdx.x;
    const int nf = *nflag_g;

    for (int fi = blockIdx.x; fi < nf; fi += 128) {
        const int r = flist[fi];
        if (tid < 32) ((float4*)xrow)[tid] = ((const float4*)(x + (size_t)r * DD))[tid];
        __syncthreads();
        int c0 = tid * 4;
        float s0 = 0.f, s1 = 0.f, s2 = 0.f, s3 = 0.f;
        #pragma unroll 8
        for (int d = 0; d < DD; d++) {
            float xv = xrow[d];
            float4 ev = *(const float4*)(e + (size_t)d * KC + c0);
            s0 = fmaf(xv, ev.x, s0); s1 = fmaf(xv, ev.y, s1);
            s2 = fmaf(xv, ev.z, s2); s3 = fmaf(xv, ev.w, s3);
        }
        float dv0 = s2g[c0 + 0] - 2.f * s0;
        float dv1 = s2g[c0 + 1] - 2.f * s1;
        float dv2 = s2g[c0 + 2] - 2.f * s2;
        float dv3 = s2g[c0 + 3] - 2.f * s3;
        float bv = dv0; int bi = c0;
        if (dv1 < bv) { bv = dv1; bi = c0 + 1; }
        if (dv2 < bv) { bv = dv2; bi = c0 + 2; }
        if (dv3 < bv) { bv = dv3; bi = c0 + 3; }
        rv[tid] = bv; ri[tid] = bi;
        __syncthreads();
        if (tid == 0) {
            float b = rv[0]; int bidx = ri[0];
            for (int t = 1; t < 256; t++)
                if (rv[t] < b) { b = rv[t]; bidx = ri[t]; }
            kfix = bidx;
        }
        __syncthreads();
        float ls = 0.f;
        if (tid < 128) {
            float q = eT[(size_t)kfix * DD + tid];
            float xv = xrow[tid];
            out_q[(size_t)r * DD + tid] = q;
            float f = q - xv;
            ls = f * f;
        }
        #pragma unroll
        for (int off = 32; off > 0; off >>= 1) ls += __shfl_down(ls, off, 64);
        if ((tid & 63) == 0 && tid < 128) wred[tid >> 6] = ls;
        __syncthreads();
        if (tid == 0) atomicAdd(loss_acc, (double)(wred[0] + wred[1]));
        __syncthreads();
    }
}

// ================= finalize =================
__global__ void k_finalize(const double* __restrict__ loss_acc,
                           float* __restrict__ out_loss) {
    double m = loss_acc[0] / 4194304.0;
    out_loss[0] = (float)(0.25 * m + m);
}

extern "C" void kernel_launch(void* const* d_in, const int* in_sizes, int n_in,
                              void* d_out, int out_size, void* d_ws, size_t ws_size,
                              hipStream_t stream) {
    const float* x = (const float*)d_in[0];
    const float* e = (const float*)d_in[1];
    float* out_q      = (float*)d_out;
    float* out_loss   = out_q + (size_t)NROWS * DD;
    float* out_scales = out_loss + 1;

    char* ws = (char*)d_ws;
    double* loss_acc     = (double*)(ws + 0);
    int*    nflag_g      = (int*)(ws + 8);
    float*  s2g          = (float*)(ws + 1024);
    float*  pv0          = (float*)(ws + 16384);
    float*  pv1          = (float*)(ws + 1064960);
    int*    pi0          = (int*)(ws + 2113536);
    float*  eT           = (float*)(ws + 3162112);
    unsigned short* a_sw = (unsigned short*)(ws + 3686400);
    // kml/flist alias a_sw (dead after k_main): 128 KB + 128 KB within 512 KB
    int*    kml          = (int*)(ws + 3686400);
    int*    flist        = (int*)(ws + 3686400 + 131072);

    hipMemsetAsync(ws, 0, 16, stream);
    k_prep_cd<<<644, 256, 0, stream>>>(e, a_sw, eT, s2g, out_scales);
    k_main<<<2048, 256, 0, stream>>>(x, a_sw, s2g, pv0, pv1, pi0);
    k_merge<<<NROWS / 256, 256, 0, stream>>>(pv0, pv1, pi0, kml, flist, nflag_g);
    k_gather<<<NROWS / 32, 256, 0, stream>>>(x, eT, kml, out_q, loss_acc);
    k_fix<<<128, 256, 0, stream>>>(x, e, eT, s2g, flist, nflag_g, out_q, loss_acc);
    k_finalize<<<1, 1, 0, stream>>>(loss_acc, out_loss);
}